// Round 6
// baseline (851.124 us; speedup 1.0000x reference)
//
#include <hip/hip_runtime.h>
#include <hip/hip_bf16.h>

#define N_ATOMS 10000
#define N_PAIRS 320000
#define C_ 64
#define NB_ 10

typedef short bf16x8 __attribute__((ext_vector_type(8)));
typedef float f32x4 __attribute__((ext_vector_type(4)));

__device__ __forceinline__ float bf2f(__hip_bfloat16 x) { return __bfloat162float(x); }
__device__ __forceinline__ float ldf(const void* p, int i, int isf32) {
    return isf32 ? ((const float*)p)[i] : bf2f(((const __hip_bfloat16*)p)[i]);
}
__device__ __forceinline__ short f2bs(float x) {
    __hip_bfloat16 h = __float2bfloat16(x);
    return *reinterpret_cast<short*>(&h);
}
__device__ __forceinline__ float bs2f(unsigned short s) {
    return __uint_as_float(((unsigned)s) << 16);
}
// fast tanh: 1 - 2/(exp(2x)+1). err ~1e-6, saturates correctly at +-inf.
__device__ __forceinline__ float tanh_fast(float x) {
    const float e = __expf(2.0f * x);
    return 1.0f - 2.0f * __builtin_amdgcn_rcpf(e + 1.0f);
}

// wbuf f32 offsets
#define W_PPREW1 0
#define W_PPREB1 4096
#define W_PPREW2 4160
#define W_PPREB2 8256
#define W_PIW    8320
#define W_PIB    90240
#define W_IIW    90880
#define W_PPOSTW1 99072
#define W_PPOSTW2 107264
#define W_EQW    111360
#define W_Q1W    115456
#define W_Q1B    123648
#define W_Q2W    123712
#define W_Q2B    131904
#define W_TOTAL  132032

__device__ __forceinline__ void probe_body(const void* d3, int* flag)
{
    float sf = 0.f, sb = 0.f;
    const float* f = (const float*)d3;
    const __hip_bfloat16* b = (const __hip_bfloat16*)d3;
    for (int r = 0; r < 4; r++) {
        float x = f[r*3], y = f[r*3+1], z = f[r*3+2];
        float n = x*x + y*y + z*z;
        sf += isfinite(n) ? fabsf(n - 1.f) : 1e30f;
        float xb = bf2f(b[r*3]), yb = bf2f(b[r*3+1]), zb = bf2f(b[r*3+2]);
        float nb = xb*xb + yb*yb + zb*zb;
        sb += isfinite(nb) ? fabsf(nb - 1.f) : 1e30f;
    }
    *flag = (sf < sb) ? 1 : 0;
}

// ---------------- probe (fallback path only) ----------------
__global__ void k_probe(const void* __restrict__ d3, int* __restrict__ flag)
{
    if (threadIdx.x == 0 && blockIdx.x == 0) probe_body(d3, flag);
}

// ---------------- probe + pair histogram (merged launch) ----------------
__global__ __launch_bounds__(256) void k_probe_hist(
    const void* __restrict__ d3, int* __restrict__ flag,
    const int* __restrict__ ind2, int* __restrict__ cnt)
{
    if (blockIdx.x == 0 && threadIdx.x == 0) probe_body(d3, flag);
    const int p = blockIdx.x * 256 + threadIdx.x;
    if (p < N_PAIRS) atomicAdd(&cnt[ind2[2 * p]], 1);
}

// ---------------- weight convert + scan (merged launch) ----------------
// blocks [0,516): gather all weights into f32 wbuf.
// block 516 (fused path only): exclusive-scan cnt -> offs, seed cur.
__global__ __launch_bounds__(256) void k_convert_scan(
    const void* s0, const void* s1, const void* s2, const void* s3,
    const void* s4, const void* s5, const void* s6, const void* s7,
    const void* s8, const void* s9, const void* s10, const void* s11,
    const void* s12, const void* s13,
    float* __restrict__ wbuf, const int* __restrict__ flagp,
    const int* __restrict__ cnt, int* __restrict__ offs, int* __restrict__ cur)
{
    __shared__ int part[256];
    __shared__ int base[257];
    if (blockIdx.x < 516) {
        const int idx = blockIdx.x * 256 + threadIdx.x;
        if (idx >= W_TOTAL) return;
        const int isf32 = *flagp;
        const int offw[15] = {W_PPREW1, W_PPREB1, W_PPREW2, W_PPREB2, W_PIW, W_PIB,
                              W_IIW, W_PPOSTW1, W_PPOSTW2, W_EQW, W_Q1W, W_Q1B,
                              W_Q2W, W_Q2B, W_TOTAL};
        const void* srcs[14] = {s0,s1,s2,s3,s4,s5,s6,s7,s8,s9,s10,s11,s12,s13};
        int t = 0;
        while (idx >= offw[t + 1]) t++;
        wbuf[idx] = ldf(srcs[t], idx - offw[t], isf32);
        return;
    }
    // ---- scan role ----
    const int t = threadIdx.x;
    const int lo = t * 40, hi = (lo + 40 < N_ATOMS) ? lo + 40 : N_ATOMS;
    int s = 0;
    for (int b = lo; b < hi; b++) s += cnt[b];
    part[t] = s;
    __syncthreads();
    if (t == 0) {
        int run = 0;
        for (int i = 0; i < 256; i++) { base[i] = run; run += part[i]; }
        base[256] = run;
    }
    __syncthreads();
    int run = base[t];
    for (int b = lo; b < hi; b++) { offs[b] = run; cur[b] = run; run += cnt[b]; }
    if (t == 0) offs[N_ATOMS] = base[256];
}

// ---------------- pack + p1_in + scatter (merged launch) ----------------
// blocks [0,352): pack piWB2 (merged per-cc 32KB tiles: hi at +0, lo at +8192
//   shorts) and iiWh/iiWl.
// blocks [352,2852): p1_in = tanh(tanh(p1 W1 + b1) W2 + b2), hi/lo bf16 split.
// blocks [2852,4102) (fused path only): scatter perm by atom.
__global__ __launch_bounds__(256) void k_prep_scatter(
    const float* __restrict__ wbuf,
    short* __restrict__ piWB2,
    short* __restrict__ iiWh, short* __restrict__ iiWl,
    const void* __restrict__ p1, const int* __restrict__ flagp,
    unsigned short* __restrict__ p1h, unsigned short* __restrict__ p1l,
    const int* __restrict__ ind2, int* __restrict__ cur, int* __restrict__ perm)
{
    __shared__ float x[4][C_];
    __shared__ float h[4][C_];
    if (blockIdx.x >= 2852) {
        const int p = (blockIdx.x - 2852) * 256 + threadIdx.x;
        if (p < N_PAIRS) {
            const int pos = atomicAdd(&cur[ind2[2 * p]], 1);
            perm[pos] = p;
        }
        return;
    }
    if (blockIdx.x < 352) {
        int idx = blockIdx.x * 256 + threadIdx.x;
        if (idx < 81920) {
            const int j = idx & 7, lane = (idx >> 3) & 63, s = (idx >> 9) & 3, T = idx >> 11;
            const int k = s * 32 + (lane >> 4) * 8 + j;
            const int colp = T * 16 + (lane & 15);
            const int b = colp >> 6, c = colp & 63;
            const float v = wbuf[W_PIW + k * 640 + c * 10 + b];
            const short hs = f2bs(v);
            const int cc = idx >> 13, e = idx & 8191;
            piWB2[cc * 16384 + e] = hs;
            piWB2[cc * 16384 + 8192 + e] = f2bs(v - bs2f((unsigned short)hs));
            return;
        }
        idx -= 81920;
        if (idx < 8192) {
            const int j = idx & 7, lane = (idx >> 3) & 63, s2 = (idx >> 9) & 1, ct = idx >> 10;
            const int k = s2 * 32 + (lane >> 4) * 8 + j;
            const int col = ct * 16 + (lane & 15);
            const float wv = wbuf[W_IIW + k * 128 + col];
            const short hs = f2bs(wv);
            iiWh[idx] = hs;
            iiWl[idx] = f2bs(wv - bs2f((unsigned short)hs));
        }
        return;
    }
    // ---- p1in role ----
    const float* W1 = wbuf + W_PPREW1;
    const float* b1 = wbuf + W_PPREB1;
    const float* W2 = wbuf + W_PPREW2;
    const float* b2 = wbuf + W_PPREB2;
    const int isf32 = *flagp;
    const int t = threadIdx.x;
    const int slot = t >> 6, c = t & 63;
    const int atom = (blockIdx.x - 352) * 4 + slot;
    x[slot][c] = ldf(p1, atom * C_ + c, isf32);
    __syncthreads();
    float acc = b1[c];
    for (int k = 0; k < C_; k++) acc += x[slot][k] * W1[k * C_ + c];
    h[slot][c] = tanh_fast(acc);
    __syncthreads();
    acc = b2[c];
    for (int k = 0; k < C_; k++) acc += h[slot][k] * W2[k * C_ + c];
    const float f = tanh_fast(acc);
    const short hs = f2bs(f);
    p1h[atom * C_ + c] = (unsigned short)hs;
    p1l[atom * C_ + c] = (unsigned short)f2bs(f - bs2f((unsigned short)hs));
}

// ---------------- permute pair inputs into sorted order + v accumulation ----------------
__global__ __launch_bounds__(256) void k_gatherperm(
    const int* __restrict__ ind2, const void* __restrict__ basis,
    const void* __restrict__ d3, const void* __restrict__ fc,
    const int* __restrict__ perm, const int* __restrict__ flagp,
    int* __restrict__ ind2P, float* __restrict__ basisP,
    float* __restrict__ d3P, float* __restrict__ fcP, float* __restrict__ v)
{
    const int q = blockIdx.x * 256 + threadIdx.x;
    if (q >= N_PAIRS) return;
    const int isf32 = *flagp;
    const int p = perm[q];
    const int2 ij = ((const int2*)ind2)[p];
    ((int2*)ind2P)[q] = ij;
    const float f = ldf(fc, p, isf32);
    fcP[q] = f;
    float dd[3];
    #pragma unroll
    for (int x = 0; x < 3; x++) {
        dd[x] = ldf(d3, 3 * p + x, isf32);
        d3P[3 * q + x] = dd[x];
    }
    #pragma unroll
    for (int x = 0; x < 3; x++) atomicAdd(&v[ij.x * 3 + x], dd[x] * f);
    #pragma unroll
    for (int b = 0; b < 10; b++) basisP[10 * q + b] = ldf(basis, 10 * p + b, isf32);
}

// ---------------- fused per-pair MFMA + sorted segment-reduce ----------------
// v6 = v5 + (a) register-prefetch double-buffered GEMM1 staging: tile cc+1 is
// loaded to regs while cc's MFMAs run; ds_write after the reads-done barrier.
// Pure __syncthreads semantics (its vmcnt(0) drain is exactly where the loads
// must have landed) -- race-free by construction, unlike the v3/v4 DMA path.
// No __launch_bounds__ VGPR cap (round-2's spill cause). (b) XCD-aware block
// swizzle: consecutive sorted-pair chunks stay on one XCD's L2.
__global__ __launch_bounds__(256) void k_pairs_fused(
    const int* __restrict__ ind2P, const float* __restrict__ basisP,
    const float* __restrict__ d3P, const float* __restrict__ fcP,
    const void* __restrict__ p3,
    const float* __restrict__ wbuf,
    const short* __restrict__ piWB2,
    const short* __restrict__ iiWh, const short* __restrict__ iiWl,
    const unsigned short* __restrict__ p1h, const unsigned short* __restrict__ p1l,
    const int* __restrict__ flagp, const float* __restrict__ vglob,
    float* __restrict__ p1scat, float* __restrict__ p3acc)
{
    // LDS overlay plan (SH = 33280 B; total block LDS ~40.9KB -> 4 blocks/CU):
    //   [0,32768)  Bbuf (merged hi|lo stage)      -- GEMM1 only
    //   [0,17408)  preL (GEMM1->GEMM2 transform)  -- after GEMM1 barrier
    //   [0,33280)  ipL  64 pairs x 130 f32        -- after ah2 barrier
    __shared__ __align__(16) char SH[33280];
    __shared__ float basisL[640];
    __shared__ float biasT[640];
    __shared__ int sIL[65], sJL[64];
    __shared__ float d3L[64][3], t3L[64][3], tbL[64];

    unsigned short* Bbuf = (unsigned short*)SH;
    float* preL = (float*)SH;
    float* ipL  = (float*)SH;

    const int t = threadIdx.x;
    // XCD swizzle: 5000 blocks = 8 XCDs x 625; block b sits on XCD b%8; give
    // each XCD a contiguous chunk of sorted-pair space.
    const int bid = blockIdx.x;
    const int P0 = ((bid & 7) * 625 + (bid >> 3)) * 64;
    const int isf32 = *flagp;
    const int lane = t & 63;
    const int w = t >> 6;
    const int lc = lane & 15;
    const int quad = lane >> 4;

    // prefetch GEMM1 tile 0 into regs (latency overlaps the setup below)
    uint4 stg[8];
    {
        const uint4* g = (const uint4*)piWB2;
        #pragma unroll
        for (int r = 0; r < 8; r++) stg[r] = g[r * 256 + t];
    }

    if (t < 64) {
        int2 ij = ((const int2*)ind2P)[P0 + t];
        sIL[t] = ij.x; sJL[t] = ij.y;
        const float vi0 = vglob[ij.x * 3 + 0], vi1 = vglob[ij.x * 3 + 1], vi2 = vglob[ij.x * 3 + 2];
        const float d0 = d3P[(P0 + t) * 3 + 0];
        const float d1 = d3P[(P0 + t) * 3 + 1];
        const float d2 = d3P[(P0 + t) * 3 + 2];
        d3L[t][0] = d0; d3L[t][1] = d1; d3L[t][2] = d2;
        const float proj = vi0 * d0 + vi1 * d1 + vi2 * d2;
        const float w0 = vi0 - proj * d0, w1 = vi1 - proj * d1, w2v = vi2 - proj * d2;
        const float w2 = w0 * w0 + w1 * w1 + w2v * w2v;
        const float g = w2 / (w2 + 1e-4f);
        const float rs = rsqrtf(w2 + 1e-6f);
        t3L[t][0] = w0 * rs * g; t3L[t][1] = w1 * rs * g; t3L[t][2] = w2v * rs * g;
        const float f = fcP[P0 + t];
        tbL[t] = g * f * f;
    }
    if (t == 64) sIL[64] = -1;   // sentinel: forces segment flush at m=63
    for (int e = t; e < 640; e += 256) basisL[e] = basisP[P0 * 10 + e];
    // bias transposed into LDS: biasT[cc*64+c]
    for (int e = t; e < 640; e += 256) biasT[e] = wbuf[W_PIB + (e & 63) * 10 + (e >> 6)];
    __syncthreads();   // setup visible; stg tile-0 loads also drained here

    // A-frags: row m = lc (pair w*16+lc), k = s*32 + quad*8 + j
    bf16x8 ah[4], al[4];
    {
        const int ia = sIL[w * 16 + lc];
        const int ja = sJL[w * 16 + lc];
        #pragma unroll
        for (int s = 0; s < 4; s++) {
            const int atom = (s < 2) ? ia : ja;
            const int off = atom * 64 + (s & 1) * 32 + quad * 8;
            ah[s] = *(const bf16x8*)(p1h + off);
            al[s] = *(const bf16x8*)(p1l + off);
        }
    }

    // GEMM1: acc = Xh*Wh + Xl*Wh + Xh*Wl  (drop lo*lo)
    float sr[4][4];
    #pragma unroll
    for (int r = 0; r < 4; r++)
        #pragma unroll
        for (int ph = 0; ph < 4; ph++) sr[r][ph] = 0.f;

    for (int cc = 0; cc < 10; cc++) {
        {   // publish prefetched tile cc
            uint4* ldst = (uint4*)Bbuf;
            #pragma unroll
            for (int r = 0; r < 8; r++) ldst[r * 256 + t] = stg[r];
        }
        __syncthreads();                  // tile staged
        if (cc < 9) {                     // issue next-tile loads under the MFMAs
            const uint4* g = (const uint4*)(piWB2 + (cc + 1) * 16384);
            #pragma unroll
            for (int r = 0; r < 8; r++) stg[r] = g[r * 256 + t];
        }
        #pragma unroll
        for (int tt = 0; tt < 4; tt++) {
            f32x4 acc = {0.f, 0.f, 0.f, 0.f};
            #pragma unroll
            for (int s = 0; s < 4; s++) {
                const int e = ((tt * 4 + s) * 64 + lane) * 8;
                bf16x8 bh = *(const bf16x8*)&Bbuf[e];
                bf16x8 bl = *(const bf16x8*)&Bbuf[8192 + e];
                acc = __builtin_amdgcn_mfma_f32_16x16x32_bf16(ah[s], bh, acc, 0, 0, 0);
                acc = __builtin_amdgcn_mfma_f32_16x16x32_bf16(al[s], bh, acc, 0, 0, 0);
                acc = __builtin_amdgcn_mfma_f32_16x16x32_bf16(ah[s], bl, acc, 0, 0, 0);
            }
            const float bias = biasT[cc * 64 + tt * 16 + lc];
            #pragma unroll
            for (int r = 0; r < 4; r++) {
                const int m = w * 16 + quad * 4 + r;
                const float h = tanh_fast(acc[r] + bias);
                sr[r][tt] += h * basisL[m * 10 + cc];
            }
        }
        __syncthreads();   // reads of Bbuf done; stg loads drained (vmcnt 0)
    }

    // pre -> LDS (C-layout to A-layout transform); Bbuf dead
    #pragma unroll
    for (int r = 0; r < 4; r++)
        #pragma unroll
        for (int ph = 0; ph < 4; ph++)
            preL[(w * 16 + quad * 4 + r) * 68 + ph * 16 + lc] = sr[r][ph];
    __syncthreads();

    bf16x8 ah2[2], al2[2];
    {
        const int row = w * 16 + lc;
        #pragma unroll
        for (int s2 = 0; s2 < 2; s2++) {
            const float* pr2 = &preL[row * 68 + s2 * 32 + quad * 8];
            #pragma unroll
            for (int j = 0; j < 8; j++) {
                const float x = pr2[j];
                const short hs = f2bs(x);
                ah2[s2][j] = hs;
                al2[s2][j] = f2bs(x - bs2f((unsigned short)hs));
            }
        }
    }
    __syncthreads();   // preL reads done before ipL overlay writes

    // Phase-B chunk-0 gather issued HERE: overlaps GEMM2's MFMAs below and
    // completes at the next __syncthreads' vmcnt drain.
    float pv0[16];
    if (t < 192) {
        #pragma unroll
        for (int u = 0; u < 16; u++) pv0[u] = ldf(p3, sJL[u] * 192 + t, isf32);
    }

    // GEMM2: i_pair -> LDS (stride 130 keeps banks at 2-way = free)
    #pragma unroll
    for (int ct = 0; ct < 8; ct++) {
        f32x4 acc = {0.f, 0.f, 0.f, 0.f};
        #pragma unroll
        for (int s2 = 0; s2 < 2; s2++) {
            bf16x8 bh = *(const bf16x8*)&iiWh[((ct * 2 + s2) * 64 + lane) * 8];
            bf16x8 bl = *(const bf16x8*)&iiWl[((ct * 2 + s2) * 64 + lane) * 8];
            acc = __builtin_amdgcn_mfma_f32_16x16x32_bf16(ah2[s2], bh, acc, 0, 0, 0);
            acc = __builtin_amdgcn_mfma_f32_16x16x32_bf16(al2[s2], bh, acc, 0, 0, 0);
            acc = __builtin_amdgcn_mfma_f32_16x16x32_bf16(ah2[s2], bl, acc, 0, 0, 0);
        }
        const int ch = ct * 16 + lc;
        #pragma unroll
        for (int r = 0; r < 4; r++) {
            const int m = w * 16 + quad * 4 + r;
            ipL[m * 130 + ch] = tanh_fast(acc[r]);
        }
    }
    __syncthreads();   // ipL published (pv0 also complete here)

    if (t < 192) {
        // Phase B (waves 0-2): p3 message segment-sum, one x-component per wave
        const int x = t >> 6, cc2 = t & 63;
        float acc = 0.f;
        #pragma unroll
        for (int blk = 0; blk < 4; blk++) {
            float pv[16];
            if (blk == 0) {
                #pragma unroll
                for (int u = 0; u < 16; u++) pv[u] = pv0[u];
            } else {
                #pragma unroll
                for (int u = 0; u < 16; u++)
                    pv[u] = ldf(p3, sJL[blk * 16 + u] * 192 + t, isf32);
            }
            #pragma unroll
            for (int u = 0; u < 16; u++) {
                const int m = blk * 16 + u;
                const float ipb = ipL[m * 130 + 64 + cc2];
                acc += (pv[u] + d3L[m][x]) * ipb + t3L[m][x] * (ipb * tbL[m]);
                if (sIL[m + 1] != sIL[m]) {
                    atomicAdd(&p3acc[(size_t)sIL[m] * 192 + t], acc);
                    acc = 0.f;
                }
            }
        }
    } else {
        // Phase A (wave 3): p1scat segment-sum, 2 channels per thread
        const int ch0 = t - 192;
        float a0 = 0.f, a1 = 0.f;
        #pragma unroll 8
        for (int m = 0; m < 64; m++) {
            a0 += ipL[m * 130 + ch0];
            a1 += ipL[m * 130 + 64 + ch0];
            if (sIL[m + 1] != sIL[m]) {
                const size_t base = (size_t)sIL[m] * 128;
                atomicAdd(&p1scat[base + ch0], a0);
                atomicAdd(&p1scat[base + 64 + ch0], a1);
                a0 = 0.f; a1 = 0.f;
            }
        }
    }
}

// ---------------- legacy atomic-path per-pair kernel (fallback) ----------------
__global__ __launch_bounds__(256) void k_pairs_atomic(
    const int* __restrict__ ind2, const void* __restrict__ basis,
    const void* __restrict__ d3, const void* __restrict__ fc,
    const void* __restrict__ p3,
    const float* __restrict__ wbuf,
    const short* __restrict__ piWB2,
    const short* __restrict__ iiWh, const short* __restrict__ iiWl,
    const unsigned short* __restrict__ p1h, const unsigned short* __restrict__ p1l,
    const int* __restrict__ flagp, const float* __restrict__ vglob,
    float* __restrict__ outA, float* __restrict__ outB)
{
    __shared__ __align__(16) unsigned short Bbuf[8192];
    __shared__ __align__(16) char SH[17408];
    __shared__ float basisL[640];
    __shared__ int sIL[64], sJL[64];
    __shared__ float d3L[64][3], t3L[64][3], tbL[64];

    float* preL = (float*)SH;
    float* i1bL = (float*)SH;

    const int t = threadIdx.x;
    const int P0 = blockIdx.x * 64;
    const int isf32 = *flagp;
    const int lane = t & 63;
    const int w = t >> 6;
    const int lc = lane & 15;
    const int quad = lane >> 4;

    if (t < 64) {
        int2 ij = ((const int2*)ind2)[P0 + t];
        sIL[t] = ij.x; sJL[t] = ij.y;
    }
    for (int e = t; e < 640; e += 256) basisL[e] = ldf(basis, P0 * 10 + e, isf32);
    __syncthreads();

    bf16x8 ah[4], al[4];
    {
        const int ia = sIL[w * 16 + lc];
        const int ja = sJL[w * 16 + lc];
        #pragma unroll
        for (int s = 0; s < 4; s++) {
            const int atom = (s < 2) ? ia : ja;
            const int off = atom * 64 + (s & 1) * 32 + quad * 8;
            ah[s] = *(const bf16x8*)(p1h + off);
            al[s] = *(const bf16x8*)(p1l + off);
        }
    }

    float sr[4][4];
    #pragma unroll
    for (int r = 0; r < 4; r++)
        #pragma unroll
        for (int ph = 0; ph < 4; ph++) sr[r][ph] = 0.f;

    for (int cc = 0; cc < 10; cc++) {
        f32x4 acc[4];
        #pragma unroll
        for (int tt = 0; tt < 4; tt++) acc[tt] = (f32x4){0.f, 0.f, 0.f, 0.f};

        __syncthreads();
        {
            const uint4* gsrc = (const uint4*)(piWB2 + cc * 16384);
            uint4* ldst = (uint4*)Bbuf;
            #pragma unroll
            for (int r = 0; r < 4; r++) ldst[r * 256 + t] = gsrc[r * 256 + t];
        }
        __syncthreads();
        #pragma unroll
        for (int tt = 0; tt < 4; tt++) {
            #pragma unroll
            for (int s = 0; s < 4; s++) {
                bf16x8 bfr = *(const bf16x8*)&Bbuf[((tt * 4 + s) * 64 + lane) * 8];
                acc[tt] = __builtin_amdgcn_mfma_f32_16x16x32_bf16(ah[s], bfr, acc[tt], 0, 0, 0);
                acc[tt] = __builtin_amdgcn_mfma_f32_16x16x32_bf16(al[s], bfr, acc[tt], 0, 0, 0);
            }
        }
        __syncthreads();
        {
            const uint4* gsrc = (const uint4*)(piWB2 + cc * 16384 + 8192);
            uint4* ldst = (uint4*)Bbuf;
            #pragma unroll
            for (int r = 0; r < 4; r++) ldst[r * 256 + t] = gsrc[r * 256 + t];
        }
        __syncthreads();
        #pragma unroll
        for (int tt = 0; tt < 4; tt++) {
            #pragma unroll
            for (int s = 0; s < 4; s++) {
                bf16x8 bfr = *(const bf16x8*)&Bbuf[((tt * 4 + s) * 64 + lane) * 8];
                acc[tt] = __builtin_amdgcn_mfma_f32_16x16x32_bf16(ah[s], bfr, acc[tt], 0, 0, 0);
            }
            const int c = tt * 16 + lc;
            const float bias = wbuf[W_PIB + c * 10 + cc];
            #pragma unroll
            for (int r = 0; r < 4; r++) {
                const int m = w * 16 + quad * 4 + r;
                const float h = tanh_fast(acc[tt][r] + bias);
                sr[r][tt] += h * basisL[m * 10 + cc];
            }
        }
    }

    #pragma unroll
    for (int r = 0; r < 4; r++)
        #pragma unroll
        for (int ph = 0; ph < 4; ph++)
            preL[(w * 16 + quad * 4 + r) * 68 + ph * 16 + lc] = sr[r][ph];
    __syncthreads();

    bf16x8 ah2[2], al2[2];
    {
        const int row = w * 16 + lc;
        #pragma unroll
        for (int s2 = 0; s2 < 2; s2++) {
            const float* pr2 = &preL[row * 68 + s2 * 32 + quad * 8];
            #pragma unroll
            for (int j = 0; j < 8; j++) {
                const float x = pr2[j];
                const short hs = f2bs(x);
                ah2[s2][j] = hs;
                al2[s2][j] = f2bs(x - bs2f((unsigned short)hs));
            }
        }
    }
    __syncthreads();

    #pragma unroll
    for (int ct = 0; ct < 8; ct++) {
        f32x4 acc = {0.f, 0.f, 0.f, 0.f};
        #pragma unroll
        for (int s2 = 0; s2 < 2; s2++) {
            bf16x8 bh = *(const bf16x8*)&iiWh[((ct * 2 + s2) * 64 + lane) * 8];
            bf16x8 bl = *(const bf16x8*)&iiWl[((ct * 2 + s2) * 64 + lane) * 8];
            acc = __builtin_amdgcn_mfma_f32_16x16x32_bf16(ah2[s2], bh, acc, 0, 0, 0);
            acc = __builtin_amdgcn_mfma_f32_16x16x32_bf16(al2[s2], bh, acc, 0, 0, 0);
            acc = __builtin_amdgcn_mfma_f32_16x16x32_bf16(ah2[s2], bl, acc, 0, 0, 0);
        }
        const int ch = ct * 16 + lc;
        #pragma unroll
        for (int r = 0; r < 4; r++) {
            const int m = w * 16 + quad * 4 + r;
            const float val = tanh_fast(acc[r]);
            atomicAdd(&outA[(size_t)sIL[m] * 128 + ch], val);
            if (ch >= 64) i1bL[m * 64 + (ch - 64)] = val;
        }
    }

    __syncthreads();
    if (t < 64) {
        const int m = t;
        const int ia = sIL[m];
        const float vi0 = vglob[ia * 3 + 0], vi1 = vglob[ia * 3 + 1], vi2 = vglob[ia * 3 + 2];
        const float d0 = ldf(d3, (P0 + m) * 3 + 0, isf32);
        const float d1 = ldf(d3, (P0 + m) * 3 + 1, isf32);
        const float d2 = ldf(d3, (P0 + m) * 3 + 2, isf32);
        d3L[m][0] = d0; d3L[m][1] = d1; d3L[m][2] = d2;
        const float proj = vi0 * d0 + vi1 * d1 + vi2 * d2;
        const float w0 = vi0 - proj * d0, w1 = vi1 - proj * d1, w2v = vi2 - proj * d2;
        const float w2 = w0 * w0 + w1 * w1 + w2v * w2v;
        const float g = w2 / (w2 + 1e-4f);
        const float rs = rsqrtf(w2 + 1e-6f);
        t3L[m][0] = w0 * rs * g; t3L[m][1] = w1 * rs * g; t3L[m][2] = w2v * rs * g;
        const float f = ldf(fc, P0 + m, isf32);
        tbL[m] = g * f * f;
    }
    __syncthreads();
    const int c = lane;
    #pragma unroll 4
    for (int mm = 0; mm < 16; mm++) {
        const int m = w * 16 + mm;
        const float bv = i1bL[m * 64 + c];
        const float coef = bv * tbL[m];
        #pragma unroll
        for (int x = 0; x < 3; x++) {
            const float p3v = ldf(p3, sJL[m] * 192 + x * 64 + c, isf32);
            atomicAdd(&outB[(size_t)sIL[m] * 192 + x * 64 + c],
                      p3v * bv + d3L[m][x] * bv + t3L[m][x] * coef);
        }
    }
}

// ---------------- per-atom epilogue ----------------
__global__ __launch_bounds__(256) void k_final(
    const float* __restrict__ p1scat, const float* __restrict__ p3acc,
    const float* __restrict__ wbuf, const int* __restrict__ flagp,
    void* __restrict__ out)
{
    const float* ppW1 = wbuf + W_PPOSTW1;
    const float* ppW2 = wbuf + W_PPOSTW2;
    const float* eqW  = wbuf + W_EQW;
    const float* q1W  = wbuf + W_Q1W;
    const float* q1b  = wbuf + W_Q1B;
    const float* q2W  = wbuf + W_Q2W;
    const float* q2b  = wbuf + W_Q2B;
    const int isf32 = *flagp;

    __shared__ float s1[4][128];
    __shared__ float hA[4][64];
    __shared__ float cat[4][128];
    __shared__ float p3a[4][192];
    const int t = threadIdx.x;
    const int slot = t >> 6, c = t & 63;
    const int atom = blockIdx.x * 4 + slot;

    s1[slot][c]        = p1scat[atom * 128 + c];
    s1[slot][64 + c]   = p1scat[atom * 128 + 64 + c];
    p3a[slot][c]       = p3acc[atom * 192 + c];
    p3a[slot][64 + c]  = p3acc[atom * 192 + 64 + c];
    p3a[slot][128 + c] = p3acc[atom * 192 + 128 + c];
    __syncthreads();

    float acc = 0.f;
    for (int k = 0; k < 128; k++) acc += s1[slot][k] * ppW1[k * 64 + c];
    hA[slot][c] = tanh_fast(acc);
    __syncthreads();
    acc = 0.f;
    for (int k = 0; k < 64; k++) acc += hA[slot][k] * ppW2[k * 64 + c];
    cat[slot][c] = tanh_fast(acc);

    float pn[3];
    float dot = 0.f;
    #pragma unroll
    for (int x = 0; x < 3; x++) {
        float a = 0.f;
        for (int k = 0; k < 64; k++) a += p3a[slot][x * 64 + k] * eqW[k * 64 + c];
        pn[x] = a;
        dot += a * a;
    }
    cat[slot][64 + c] = dot;
    __syncthreads();

    acc = q1b[c];
    for (int k = 0; k < 128; k++) acc += cat[slot][k] * q1W[k * 64 + c];
    __syncthreads();
    hA[slot][c] = tanh_fast(acc);
    __syncthreads();

    float g1acc = q2b[c], g3acc = q2b[c + 64];
    for (int k = 0; k < 64; k++) {
        const float hv = hA[slot][k];
        g1acc += hv * q2W[k * 128 + c];
        g3acc += hv * q2W[k * 128 + c + 64];
    }
    const float g1 = tanh_fast(g1acc);
    const float g3 = tanh_fast(g3acc);
    if (isf32) {
        float* p1o = (float*)out;
        float* p3o = p1o + 640000;
        p1o[atom * 64 + c] = g1;
        #pragma unroll
        for (int x = 0; x < 3; x++) p3o[atom * 192 + x * 64 + c] = pn[x] * g3;
    } else {
        __hip_bfloat16* p1o = (__hip_bfloat16*)out;
        __hip_bfloat16* p3o = p1o + 640000;
        p1o[atom * 64 + c] = __float2bfloat16(g1);
        #pragma unroll
        for (int x = 0; x < 3; x++) p3o[atom * 192 + x * 64 + c] = __float2bfloat16(pn[x] * g3);
    }
}

// ---------------- v scatter (atomic fallback path only) ----------------
__global__ __launch_bounds__(256) void k_vscat(
    const int* __restrict__ ind2, const void* __restrict__ d3,
    const void* __restrict__ fc, const int* __restrict__ flagp, float* __restrict__ v)
{
    const int p = blockIdx.x * 256 + threadIdx.x;
    if (p >= N_PAIRS) return;
    const int isf32 = *flagp;
    const int ia = ind2[2 * p];
    const float f = ldf(fc, p, isf32);
    atomicAdd(&v[ia * 3 + 0], ldf(d3, p * 3 + 0, isf32) * f);
    atomicAdd(&v[ia * 3 + 1], ldf(d3, p * 3 + 1, isf32) * f);
    atomicAdd(&v[ia * 3 + 2], ldf(d3, p * 3 + 2, isf32) * f);
}

extern "C" void kernel_launch(void* const* d_in, const int* in_sizes, int n_in,
                              void* d_out, int out_size, void* d_ws, size_t ws_size,
                              hipStream_t stream)
{
    const int* ind2 = (const int*)d_in[0];
    const void* p1    = d_in[1];
    const void* p3    = d_in[2];
    const void* basis = d_in[3];
    const void* d3    = d_in[4];
    const void* fc    = d_in[5];

    char* W = (char*)d_ws;
    float* wbuf  = (float*)(W + 0);                       // 528128 B
    short* piWB2 = (short*)(W + 528128);                  // 655360 B -> 1183488
    short* iiWh  = (short*)(W + 1183488);                 // 16384 B -> 1199872
    short* iiWl  = (short*)(W + 1199872);                 // 16384 B -> 1216256
    unsigned short* p1h = (unsigned short*)(W + 1216256); // 1280000 B -> 2496256
    unsigned short* p1l = (unsigned short*)(W + 2496256); // 1280000 B -> 3776256
    int* flag = (int*)(W + 3776256);                      // 64 B -> 3776320

    const int fused = (ws_size >= 38576384ULL) ? 1 : 0;

    if (fused) {
        int* offs     = (int*)(W + 3776320);      // 40016 B -> pad 3816384
        int* cur      = (int*)(W + 3816384);      // 40000 B -> 3856384
        int* perm     = (int*)(W + 3856384);      // 1280000 B -> 5136384
        int* ind2P    = (int*)(W + 5136384);      // 2560000 B -> 7696384
        float* basisP = (float*)(W + 7696384);    // 12800000 B -> 20496384
        float* d3P    = (float*)(W + 20496384);   // 3840000 B -> 24336384
        float* fcP    = (float*)(W + 24336384);   // 1280000 B -> 25616384
        int* cnt      = (int*)(W + 25616384);     // 40000 B -> 25656384
        float* v      = (float*)(W + 25656384);   // 120000 B -> 25776384
        float* p1scat = (float*)(W + 25776384);   // 5120000 B -> 30896384
        float* p3acc  = (float*)(W + 30896384);   // 7680000 B -> ends 38576384

        // one contiguous zero: cnt + v + p1scat + p3acc
        hipMemsetAsync(cnt, 0, 40000 + 120000 + 5120000 + 7680000, stream);
        k_probe_hist<<<1250, 256, 0, stream>>>(d3, flag, ind2, cnt);
        k_convert_scan<<<517, 256, 0, stream>>>(
            d_in[6], d_in[7], d_in[8], d_in[9], d_in[10], d_in[11], d_in[12],
            d_in[13], d_in[14], d_in[15], d_in[16], d_in[17], d_in[18], d_in[19],
            wbuf, flag, cnt, offs, cur);
        k_prep_scatter<<<4102, 256, 0, stream>>>(wbuf, piWB2, iiWh, iiWl, p1, flag,
                                                 p1h, p1l, ind2, cur, perm);
        k_gatherperm<<<1250, 256, 0, stream>>>(ind2, basis, d3, fc, perm, flag,
                                               ind2P, basisP, d3P, fcP, v);
        k_pairs_fused<<<5000, 256, 0, stream>>>(ind2P, basisP, d3P, fcP, p3,
                                                wbuf, piWB2, iiWh, iiWl,
                                                p1h, p1l, flag, v, p1scat, p3acc);
        k_final<<<2500, 256, 0, stream>>>(p1scat, p3acc, wbuf, flag, d_out);
    } else {
        float* v      = (float*)(W + 3776320); // 120000 B -> 3896320
        float* p1scat = (float*)(W + 3896320); // 5120000 B -> 9016320
        float* p3acc  = (float*)(W + 9016320); // 7680000 B -> ends 16696320

        hipMemsetAsync(v, 0, 120000 + 5120000 + 7680000, stream);
        k_probe<<<1, 64, 0, stream>>>(d3, flag);
        k_convert_scan<<<516, 256, 0, stream>>>(
            d_in[6], d_in[7], d_in[8], d_in[9], d_in[10], d_in[11], d_in[12],
            d_in[13], d_in[14], d_in[15], d_in[16], d_in[17], d_in[18], d_in[19],
            wbuf, flag, nullptr, nullptr, nullptr);
        k_prep_scatter<<<2852, 256, 0, stream>>>(wbuf, piWB2, iiWh, iiWl, p1, flag,
                                                 p1h, p1l, nullptr, nullptr, nullptr);
        k_vscat<<<1250, 256, 0, stream>>>(ind2, d3, fc, flag, v);
        k_pairs_atomic<<<5000, 256, 0, stream>>>(ind2, basis, d3, fc, p3,
                                                 wbuf, piWB2, iiWh, iiWl,
                                                 p1h, p1l, flag, v,
                                                 p1scat, p3acc);
        k_final<<<2500, 256, 0, stream>>>(p1scat, p3acc, wbuf, flag, d_out);
    }
}

// Round 7
// 516.052 us; speedup vs baseline: 1.6493x; 1.6493x over previous
//
#include <hip/hip_runtime.h>
#include <hip/hip_bf16.h>

#define N_ATOMS 10000
#define N_PAIRS 320000
#define C_ 64
#define NB_ 10

typedef short bf16x8 __attribute__((ext_vector_type(8)));
typedef float f32x4 __attribute__((ext_vector_type(4)));

__device__ __forceinline__ float bf2f(__hip_bfloat16 x) { return __bfloat162float(x); }
__device__ __forceinline__ float ldf(const void* p, int i, int isf32) {
    return isf32 ? ((const float*)p)[i] : bf2f(((const __hip_bfloat16*)p)[i]);
}
__device__ __forceinline__ short f2bs(float x) {
    __hip_bfloat16 h = __float2bfloat16(x);
    return *reinterpret_cast<short*>(&h);
}
__device__ __forceinline__ float bs2f(unsigned short s) {
    return __uint_as_float(((unsigned)s) << 16);
}
// fast tanh: 1 - 2/(exp(2x)+1). err ~1e-6, saturates correctly at +-inf.
__device__ __forceinline__ float tanh_fast(float x) {
    const float e = __expf(2.0f * x);
    return 1.0f - 2.0f * __builtin_amdgcn_rcpf(e + 1.0f);
}

// wbuf f32 offsets
#define W_PPREW1 0
#define W_PPREB1 4096
#define W_PPREW2 4160
#define W_PPREB2 8256
#define W_PIW    8320
#define W_PIB    90240
#define W_IIW    90880
#define W_PPOSTW1 99072
#define W_PPOSTW2 107264
#define W_EQW    111360
#define W_Q1W    115456
#define W_Q1B    123648
#define W_Q2W    123712
#define W_Q2B    131904
#define W_TOTAL  132032

__device__ __forceinline__ int probe_eval(const void* d3)
{
    float sf = 0.f, sb = 0.f;
    const float* f = (const float*)d3;
    const __hip_bfloat16* b = (const __hip_bfloat16*)d3;
    for (int r = 0; r < 4; r++) {
        float x = f[r*3], y = f[r*3+1], z = f[r*3+2];
        float n = x*x + y*y + z*z;
        sf += isfinite(n) ? fabsf(n - 1.f) : 1e30f;
        float xb = bf2f(b[r*3]), yb = bf2f(b[r*3+1]), zb = bf2f(b[r*3+2]);
        float nb = xb*xb + yb*yb + zb*zb;
        sb += isfinite(nb) ? fabsf(nb - 1.f) : 1e30f;
    }
    return (sf < sb) ? 1 : 0;
}

// ---------------- probe (fallback path only) ----------------
__global__ void k_probe(const void* __restrict__ d3, int* __restrict__ flag)
{
    if (threadIdx.x == 0 && blockIdx.x == 0) *flag = probe_eval(d3);
}

// ---------------- probe + pair histogram + v accumulation (merged) ----------------
// flag is computed block-locally (global flag not yet ordered within this
// kernel); block 0 also publishes it for the downstream kernels.
__global__ __launch_bounds__(256) void k_probe_hist_v(
    const void* __restrict__ d3, const void* __restrict__ fc,
    int* __restrict__ flag, const int* __restrict__ ind2,
    int* __restrict__ cnt, float* __restrict__ v)
{
    __shared__ int fsh;
    if (threadIdx.x == 0) {
        const int fv = probe_eval(d3);
        fsh = fv;
        if (blockIdx.x == 0) *flag = fv;
    }
    __syncthreads();
    const int isf32 = fsh;
    const int p = blockIdx.x * 256 + threadIdx.x;
    if (p >= N_PAIRS) return;
    const int ia = ind2[2 * p];
    atomicAdd(&cnt[ia], 1);
    const float f = ldf(fc, p, isf32);
    #pragma unroll
    for (int x = 0; x < 3; x++)
        atomicAdd(&v[ia * 3 + x], ldf(d3, 3 * p + x, isf32) * f);
}

// ---------------- weight convert + scan (merged launch) ----------------
// blocks [0,516): gather all weights into f32 wbuf.
// block 516 (fused path only): exclusive-scan cnt -> offs, seed cur.
__global__ __launch_bounds__(256) void k_convert_scan(
    const void* s0, const void* s1, const void* s2, const void* s3,
    const void* s4, const void* s5, const void* s6, const void* s7,
    const void* s8, const void* s9, const void* s10, const void* s11,
    const void* s12, const void* s13,
    float* __restrict__ wbuf, const int* __restrict__ flagp,
    const int* __restrict__ cnt, int* __restrict__ offs, int* __restrict__ cur)
{
    __shared__ int part[256];
    __shared__ int base[257];
    if (blockIdx.x < 516) {
        const int idx = blockIdx.x * 256 + threadIdx.x;
        if (idx >= W_TOTAL) return;
        const int isf32 = *flagp;
        const int offw[15] = {W_PPREW1, W_PPREB1, W_PPREW2, W_PPREB2, W_PIW, W_PIB,
                              W_IIW, W_PPOSTW1, W_PPOSTW2, W_EQW, W_Q1W, W_Q1B,
                              W_Q2W, W_Q2B, W_TOTAL};
        const void* srcs[14] = {s0,s1,s2,s3,s4,s5,s6,s7,s8,s9,s10,s11,s12,s13};
        int t = 0;
        while (idx >= offw[t + 1]) t++;
        wbuf[idx] = ldf(srcs[t], idx - offw[t], isf32);
        return;
    }
    // ---- scan role ----
    const int t = threadIdx.x;
    const int lo = t * 40, hi = (lo + 40 < N_ATOMS) ? lo + 40 : N_ATOMS;
    int s = 0;
    for (int b = lo; b < hi; b++) s += cnt[b];
    part[t] = s;
    __syncthreads();
    if (t == 0) {
        int run = 0;
        for (int i = 0; i < 256; i++) { base[i] = run; run += part[i]; }
        base[256] = run;
    }
    __syncthreads();
    int run = base[t];
    for (int b = lo; b < hi; b++) { offs[b] = run; cur[b] = run; run += cnt[b]; }
    if (t == 0) offs[N_ATOMS] = base[256];
}

// ---------------- pack + p1_in + scatter (merged launch) ----------------
// blocks [0,352): pack piWB2 (merged per-cc 32KB tiles: hi at +0, lo at +8192
//   shorts) and iiWh/iiWl.
// blocks [352,2852): p1_in = tanh(tanh(p1 W1 + b1) W2 + b2), hi/lo bf16 split.
// blocks [2852,4102) (fused path only): scatter perm by atom.
__global__ __launch_bounds__(256) void k_prep_scatter(
    const float* __restrict__ wbuf,
    short* __restrict__ piWB2,
    short* __restrict__ iiWh, short* __restrict__ iiWl,
    const void* __restrict__ p1, const int* __restrict__ flagp,
    unsigned short* __restrict__ p1h, unsigned short* __restrict__ p1l,
    const int* __restrict__ ind2, int* __restrict__ cur, int* __restrict__ perm)
{
    __shared__ float x[4][C_];
    __shared__ float h[4][C_];
    if (blockIdx.x >= 2852) {
        const int p = (blockIdx.x - 2852) * 256 + threadIdx.x;
        if (p < N_PAIRS) {
            const int pos = atomicAdd(&cur[ind2[2 * p]], 1);
            perm[pos] = p;
        }
        return;
    }
    if (blockIdx.x < 352) {
        int idx = blockIdx.x * 256 + threadIdx.x;
        if (idx < 81920) {
            const int j = idx & 7, lane = (idx >> 3) & 63, s = (idx >> 9) & 3, T = idx >> 11;
            const int k = s * 32 + (lane >> 4) * 8 + j;
            const int colp = T * 16 + (lane & 15);
            const int b = colp >> 6, c = colp & 63;
            const float v = wbuf[W_PIW + k * 640 + c * 10 + b];
            const short hs = f2bs(v);
            const int cc = idx >> 13, e = idx & 8191;
            piWB2[cc * 16384 + e] = hs;
            piWB2[cc * 16384 + 8192 + e] = f2bs(v - bs2f((unsigned short)hs));
            return;
        }
        idx -= 81920;
        if (idx < 8192) {
            const int j = idx & 7, lane = (idx >> 3) & 63, s2 = (idx >> 9) & 1, ct = idx >> 10;
            const int k = s2 * 32 + (lane >> 4) * 8 + j;
            const int col = ct * 16 + (lane & 15);
            const float wv = wbuf[W_IIW + k * 128 + col];
            const short hs = f2bs(wv);
            iiWh[idx] = hs;
            iiWl[idx] = f2bs(wv - bs2f((unsigned short)hs));
        }
        return;
    }
    // ---- p1in role ----
    const float* W1 = wbuf + W_PPREW1;
    const float* b1 = wbuf + W_PPREB1;
    const float* W2 = wbuf + W_PPREW2;
    const float* b2 = wbuf + W_PPREB2;
    const int isf32 = *flagp;
    const int t = threadIdx.x;
    const int slot = t >> 6, c = t & 63;
    const int atom = (blockIdx.x - 352) * 4 + slot;
    x[slot][c] = ldf(p1, atom * C_ + c, isf32);
    __syncthreads();
    float acc = b1[c];
    for (int k = 0; k < C_; k++) acc += x[slot][k] * W1[k * C_ + c];
    h[slot][c] = tanh_fast(acc);
    __syncthreads();
    acc = b2[c];
    for (int k = 0; k < C_; k++) acc += h[slot][k] * W2[k * C_ + c];
    const float f = tanh_fast(acc);
    const short hs = f2bs(f);
    p1h[atom * C_ + c] = (unsigned short)hs;
    p1l[atom * C_ + c] = (unsigned short)f2bs(f - bs2f((unsigned short)hs));
}

// ---------------- fused per-pair MFMA + sorted segment-reduce ----------------
// v7 = v5 (the proven 239.7us structure: pure __syncthreads, transient-reg
// staging -- the reg-prefetch of v6 and the DMA pipeline of v3/v4 are both
// permanently abandoned: compiler allocates the staging array to scratch,
// 1.6 GB spill traffic) + perm-indirect input reads (k_gatherperm deleted;
// its random reads now hide under the setup/A-frag phase) + XCD-aware block
// swizzle (sorted-atom chunks stay on one XCD's L2).
__global__ __launch_bounds__(256) void k_pairs_fused(
    const int* __restrict__ ind2, const void* __restrict__ basis,
    const void* __restrict__ d3, const void* __restrict__ fc,
    const int* __restrict__ perm,
    const void* __restrict__ p3,
    const float* __restrict__ wbuf,
    const short* __restrict__ piWB2,
    const short* __restrict__ iiWh, const short* __restrict__ iiWl,
    const unsigned short* __restrict__ p1h, const unsigned short* __restrict__ p1l,
    const int* __restrict__ flagp, const float* __restrict__ vglob,
    float* __restrict__ p1scat, float* __restrict__ p3acc)
{
    // LDS overlay plan (SH = 33280 B; total block LDS ~40.9KB -> 4 blocks/CU):
    //   [0,32768)  Bbuf (merged hi|lo stage)      -- GEMM1 only
    //   [0,17408)  preL (GEMM1->GEMM2 transform)  -- after GEMM1 barrier
    //   [0,33280)  ipL  64 pairs x 130 f32        -- after ah2 barrier
    __shared__ __align__(16) char SH[33280];
    __shared__ float basisL[640];
    __shared__ float biasT[640];
    __shared__ int sIL[65], sJL[64];
    __shared__ float d3L[64][3], t3L[64][3], tbL[64];

    unsigned short* Bbuf = (unsigned short*)SH;
    float* preL = (float*)SH;
    float* ipL  = (float*)SH;

    const int t = threadIdx.x;
    // XCD swizzle: 5000 blocks = 8 XCDs x 625; block b sits on XCD b%8; give
    // each XCD a contiguous chunk of sorted-pair space.
    const int bid = blockIdx.x;
    const int P0 = ((bid & 7) * 625 + (bid >> 3)) * 64;
    const int isf32 = *flagp;
    const int lane = t & 63;
    const int w = t >> 6;
    const int lc = lane & 15;
    const int quad = lane >> 4;

    if (t < 64) {
        const int p = perm[P0 + t];
        int2 ij = ((const int2*)ind2)[p];
        sIL[t] = ij.x; sJL[t] = ij.y;
        const float vi0 = vglob[ij.x * 3 + 0], vi1 = vglob[ij.x * 3 + 1], vi2 = vglob[ij.x * 3 + 2];
        const float d0 = ldf(d3, 3 * p + 0, isf32);
        const float d1 = ldf(d3, 3 * p + 1, isf32);
        const float d2 = ldf(d3, 3 * p + 2, isf32);
        d3L[t][0] = d0; d3L[t][1] = d1; d3L[t][2] = d2;
        const float proj = vi0 * d0 + vi1 * d1 + vi2 * d2;
        const float w0 = vi0 - proj * d0, w1 = vi1 - proj * d1, w2v = vi2 - proj * d2;
        const float w2 = w0 * w0 + w1 * w1 + w2v * w2v;
        const float g = w2 / (w2 + 1e-4f);
        const float rs = rsqrtf(w2 + 1e-6f);
        t3L[t][0] = w0 * rs * g; t3L[t][1] = w1 * rs * g; t3L[t][2] = w2v * rs * g;
        const float f = ldf(fc, p, isf32);
        tbL[t] = g * f * f;
    }
    if (t == 64) sIL[64] = -1;   // sentinel: forces segment flush at m=63
    // basis gather through perm (40B rows at random offsets; hides under setup)
    for (int e = t; e < 640; e += 256) {
        const int pm = e / 10, col = e - pm * 10;
        basisL[e] = ldf(basis, perm[P0 + pm] * 10 + col, isf32);
    }
    // bias transposed into LDS: biasT[cc*64+c]
    for (int e = t; e < 640; e += 256) biasT[e] = wbuf[W_PIB + (e & 63) * 10 + (e >> 6)];
    __syncthreads();

    // A-frags: row m = lc (pair w*16+lc), k = s*32 + quad*8 + j
    bf16x8 ah[4], al[4];
    {
        const int ia = sIL[w * 16 + lc];
        const int ja = sJL[w * 16 + lc];
        #pragma unroll
        for (int s = 0; s < 4; s++) {
            const int atom = (s < 2) ? ia : ja;
            const int off = atom * 64 + (s & 1) * 32 + quad * 8;
            ah[s] = *(const bf16x8*)(p1h + off);
            al[s] = *(const bf16x8*)(p1l + off);
        }
    }

    // GEMM1: acc = Xh*Wh + Xl*Wh + Xh*Wl  (drop lo*lo)
    float sr[4][4];
    #pragma unroll
    for (int r = 0; r < 4; r++)
        #pragma unroll
        for (int ph = 0; ph < 4; ph++) sr[r][ph] = 0.f;

    for (int cc = 0; cc < 10; cc++) {
        if (cc) __syncthreads();          // prev tile reads done
        {   // stage merged 32KB hi|lo tile (transient regs; no spill)
            const uint4* gsrc = (const uint4*)(piWB2 + cc * 16384);
            uint4* ldst = (uint4*)Bbuf;
            #pragma unroll
            for (int r = 0; r < 8; r++) ldst[r * 256 + t] = gsrc[r * 256 + t];
        }
        __syncthreads();                  // tile staged
        #pragma unroll
        for (int tt = 0; tt < 4; tt++) {
            f32x4 acc = {0.f, 0.f, 0.f, 0.f};
            #pragma unroll
            for (int s = 0; s < 4; s++) {
                const int e = ((tt * 4 + s) * 64 + lane) * 8;
                bf16x8 bh = *(const bf16x8*)&Bbuf[e];
                bf16x8 bl = *(const bf16x8*)&Bbuf[8192 + e];
                acc = __builtin_amdgcn_mfma_f32_16x16x32_bf16(ah[s], bh, acc, 0, 0, 0);
                acc = __builtin_amdgcn_mfma_f32_16x16x32_bf16(al[s], bh, acc, 0, 0, 0);
                acc = __builtin_amdgcn_mfma_f32_16x16x32_bf16(ah[s], bl, acc, 0, 0, 0);
            }
            const float bias = biasT[cc * 64 + tt * 16 + lc];
            #pragma unroll
            for (int r = 0; r < 4; r++) {
                const int m = w * 16 + quad * 4 + r;
                const float h = tanh_fast(acc[r] + bias);
                sr[r][tt] += h * basisL[m * 10 + cc];
            }
        }
    }
    __syncthreads();   // last tile reads done before preL overlay

    // pre -> LDS (C-layout to A-layout transform)
    #pragma unroll
    for (int r = 0; r < 4; r++)
        #pragma unroll
        for (int ph = 0; ph < 4; ph++)
            preL[(w * 16 + quad * 4 + r) * 68 + ph * 16 + lc] = sr[r][ph];
    __syncthreads();

    bf16x8 ah2[2], al2[2];
    {
        const int row = w * 16 + lc;
        #pragma unroll
        for (int s2 = 0; s2 < 2; s2++) {
            const float* pr2 = &preL[row * 68 + s2 * 32 + quad * 8];
            #pragma unroll
            for (int j = 0; j < 8; j++) {
                const float x = pr2[j];
                const short hs = f2bs(x);
                ah2[s2][j] = hs;
                al2[s2][j] = f2bs(x - bs2f((unsigned short)hs));
            }
        }
    }
    __syncthreads();   // preL reads done before ipL overlay writes

    // Phase-B chunk-0 gather issued HERE: overlaps GEMM2's MFMAs below and
    // completes at the next __syncthreads' vmcnt drain.
    float pv0[16];
    if (t < 192) {
        #pragma unroll
        for (int u = 0; u < 16; u++) pv0[u] = ldf(p3, sJL[u] * 192 + t, isf32);
    }

    // GEMM2: i_pair -> LDS (stride 130 keeps banks at 2-way = free)
    #pragma unroll
    for (int ct = 0; ct < 8; ct++) {
        f32x4 acc = {0.f, 0.f, 0.f, 0.f};
        #pragma unroll
        for (int s2 = 0; s2 < 2; s2++) {
            bf16x8 bh = *(const bf16x8*)&iiWh[((ct * 2 + s2) * 64 + lane) * 8];
            bf16x8 bl = *(const bf16x8*)&iiWl[((ct * 2 + s2) * 64 + lane) * 8];
            acc = __builtin_amdgcn_mfma_f32_16x16x32_bf16(ah2[s2], bh, acc, 0, 0, 0);
            acc = __builtin_amdgcn_mfma_f32_16x16x32_bf16(al2[s2], bh, acc, 0, 0, 0);
            acc = __builtin_amdgcn_mfma_f32_16x16x32_bf16(ah2[s2], bl, acc, 0, 0, 0);
        }
        const int ch = ct * 16 + lc;
        #pragma unroll
        for (int r = 0; r < 4; r++) {
            const int m = w * 16 + quad * 4 + r;
            ipL[m * 130 + ch] = tanh_fast(acc[r]);
        }
    }
    __syncthreads();   // ipL published (pv0 also complete here)

    if (t < 192) {
        // Phase B (waves 0-2): p3 message segment-sum, one x-component per wave
        const int x = t >> 6, cc2 = t & 63;
        float acc = 0.f;
        #pragma unroll
        for (int blk = 0; blk < 4; blk++) {
            float pv[16];
            if (blk == 0) {
                #pragma unroll
                for (int u = 0; u < 16; u++) pv[u] = pv0[u];
            } else {
                #pragma unroll
                for (int u = 0; u < 16; u++)
                    pv[u] = ldf(p3, sJL[blk * 16 + u] * 192 + t, isf32);
            }
            #pragma unroll
            for (int u = 0; u < 16; u++) {
                const int m = blk * 16 + u;
                const float ipb = ipL[m * 130 + 64 + cc2];
                acc += (pv[u] + d3L[m][x]) * ipb + t3L[m][x] * (ipb * tbL[m]);
                if (sIL[m + 1] != sIL[m]) {
                    atomicAdd(&p3acc[(size_t)sIL[m] * 192 + t], acc);
                    acc = 0.f;
                }
            }
        }
    } else {
        // Phase A (wave 3): p1scat segment-sum, 2 channels per thread
        const int ch0 = t - 192;
        float a0 = 0.f, a1 = 0.f;
        #pragma unroll 8
        for (int m = 0; m < 64; m++) {
            a0 += ipL[m * 130 + ch0];
            a1 += ipL[m * 130 + 64 + ch0];
            if (sIL[m + 1] != sIL[m]) {
                const size_t base = (size_t)sIL[m] * 128;
                atomicAdd(&p1scat[base + ch0], a0);
                atomicAdd(&p1scat[base + 64 + ch0], a1);
                a0 = 0.f; a1 = 0.f;
            }
        }
    }
}

// ---------------- legacy atomic-path per-pair kernel (fallback) ----------------
__global__ __launch_bounds__(256) void k_pairs_atomic(
    const int* __restrict__ ind2, const void* __restrict__ basis,
    const void* __restrict__ d3, const void* __restrict__ fc,
    const void* __restrict__ p3,
    const float* __restrict__ wbuf,
    const short* __restrict__ piWB2,
    const short* __restrict__ iiWh, const short* __restrict__ iiWl,
    const unsigned short* __restrict__ p1h, const unsigned short* __restrict__ p1l,
    const int* __restrict__ flagp, const float* __restrict__ vglob,
    float* __restrict__ outA, float* __restrict__ outB)
{
    __shared__ __align__(16) unsigned short Bbuf[8192];
    __shared__ __align__(16) char SH[17408];
    __shared__ float basisL[640];
    __shared__ int sIL[64], sJL[64];
    __shared__ float d3L[64][3], t3L[64][3], tbL[64];

    float* preL = (float*)SH;
    float* i1bL = (float*)SH;

    const int t = threadIdx.x;
    const int P0 = blockIdx.x * 64;
    const int isf32 = *flagp;
    const int lane = t & 63;
    const int w = t >> 6;
    const int lc = lane & 15;
    const int quad = lane >> 4;

    if (t < 64) {
        int2 ij = ((const int2*)ind2)[P0 + t];
        sIL[t] = ij.x; sJL[t] = ij.y;
    }
    for (int e = t; e < 640; e += 256) basisL[e] = ldf(basis, P0 * 10 + e, isf32);
    __syncthreads();

    bf16x8 ah[4], al[4];
    {
        const int ia = sIL[w * 16 + lc];
        const int ja = sJL[w * 16 + lc];
        #pragma unroll
        for (int s = 0; s < 4; s++) {
            const int atom = (s < 2) ? ia : ja;
            const int off = atom * 64 + (s & 1) * 32 + quad * 8;
            ah[s] = *(const bf16x8*)(p1h + off);
            al[s] = *(const bf16x8*)(p1l + off);
        }
    }

    float sr[4][4];
    #pragma unroll
    for (int r = 0; r < 4; r++)
        #pragma unroll
        for (int ph = 0; ph < 4; ph++) sr[r][ph] = 0.f;

    for (int cc = 0; cc < 10; cc++) {
        f32x4 acc[4];
        #pragma unroll
        for (int tt = 0; tt < 4; tt++) acc[tt] = (f32x4){0.f, 0.f, 0.f, 0.f};

        __syncthreads();
        {
            const uint4* gsrc = (const uint4*)(piWB2 + cc * 16384);
            uint4* ldst = (uint4*)Bbuf;
            #pragma unroll
            for (int r = 0; r < 4; r++) ldst[r * 256 + t] = gsrc[r * 256 + t];
        }
        __syncthreads();
        #pragma unroll
        for (int tt = 0; tt < 4; tt++) {
            #pragma unroll
            for (int s = 0; s < 4; s++) {
                bf16x8 bfr = *(const bf16x8*)&Bbuf[((tt * 4 + s) * 64 + lane) * 8];
                acc[tt] = __builtin_amdgcn_mfma_f32_16x16x32_bf16(ah[s], bfr, acc[tt], 0, 0, 0);
                acc[tt] = __builtin_amdgcn_mfma_f32_16x16x32_bf16(al[s], bfr, acc[tt], 0, 0, 0);
            }
        }
        __syncthreads();
        {
            const uint4* gsrc = (const uint4*)(piWB2 + cc * 16384 + 8192);
            uint4* ldst = (uint4*)Bbuf;
            #pragma unroll
            for (int r = 0; r < 4; r++) ldst[r * 256 + t] = gsrc[r * 256 + t];
        }
        __syncthreads();
        #pragma unroll
        for (int tt = 0; tt < 4; tt++) {
            #pragma unroll
            for (int s = 0; s < 4; s++) {
                bf16x8 bfr = *(const bf16x8*)&Bbuf[((tt * 4 + s) * 64 + lane) * 8];
                acc[tt] = __builtin_amdgcn_mfma_f32_16x16x32_bf16(ah[s], bfr, acc[tt], 0, 0, 0);
            }
            const int c = tt * 16 + lc;
            const float bias = wbuf[W_PIB + c * 10 + cc];
            #pragma unroll
            for (int r = 0; r < 4; r++) {
                const int m = w * 16 + quad * 4 + r;
                const float h = tanh_fast(acc[tt][r] + bias);
                sr[r][tt] += h * basisL[m * 10 + cc];
            }
        }
    }

    #pragma unroll
    for (int r = 0; r < 4; r++)
        #pragma unroll
        for (int ph = 0; ph < 4; ph++)
            preL[(w * 16 + quad * 4 + r) * 68 + ph * 16 + lc] = sr[r][ph];
    __syncthreads();

    bf16x8 ah2[2], al2[2];
    {
        const int row = w * 16 + lc;
        #pragma unroll
        for (int s2 = 0; s2 < 2; s2++) {
            const float* pr2 = &preL[row * 68 + s2 * 32 + quad * 8];
            #pragma unroll
            for (int j = 0; j < 8; j++) {
                const float x = pr2[j];
                const short hs = f2bs(x);
                ah2[s2][j] = hs;
                al2[s2][j] = f2bs(x - bs2f((unsigned short)hs));
            }
        }
    }
    __syncthreads();

    #pragma unroll
    for (int ct = 0; ct < 8; ct++) {
        f32x4 acc = {0.f, 0.f, 0.f, 0.f};
        #pragma unroll
        for (int s2 = 0; s2 < 2; s2++) {
            bf16x8 bh = *(const bf16x8*)&iiWh[((ct * 2 + s2) * 64 + lane) * 8];
            bf16x8 bl = *(const bf16x8*)&iiWl[((ct * 2 + s2) * 64 + lane) * 8];
            acc = __builtin_amdgcn_mfma_f32_16x16x32_bf16(ah2[s2], bh, acc, 0, 0, 0);
            acc = __builtin_amdgcn_mfma_f32_16x16x32_bf16(al2[s2], bh, acc, 0, 0, 0);
            acc = __builtin_amdgcn_mfma_f32_16x16x32_bf16(ah2[s2], bl, acc, 0, 0, 0);
        }
        const int ch = ct * 16 + lc;
        #pragma unroll
        for (int r = 0; r < 4; r++) {
            const int m = w * 16 + quad * 4 + r;
            const float val = tanh_fast(acc[r]);
            atomicAdd(&outA[(size_t)sIL[m] * 128 + ch], val);
            if (ch >= 64) i1bL[m * 64 + (ch - 64)] = val;
        }
    }

    __syncthreads();
    if (t < 64) {
        const int m = t;
        const int ia = sIL[m];
        const float vi0 = vglob[ia * 3 + 0], vi1 = vglob[ia * 3 + 1], vi2 = vglob[ia * 3 + 2];
        const float d0 = ldf(d3, (P0 + m) * 3 + 0, isf32);
        const float d1 = ldf(d3, (P0 + m) * 3 + 1, isf32);
        const float d2 = ldf(d3, (P0 + m) * 3 + 2, isf32);
        d3L[m][0] = d0; d3L[m][1] = d1; d3L[m][2] = d2;
        const float proj = vi0 * d0 + vi1 * d1 + vi2 * d2;
        const float w0 = vi0 - proj * d0, w1 = vi1 - proj * d1, w2v = vi2 - proj * d2;
        const float w2 = w0 * w0 + w1 * w1 + w2v * w2v;
        const float g = w2 / (w2 + 1e-4f);
        const float rs = rsqrtf(w2 + 1e-6f);
        t3L[m][0] = w0 * rs * g; t3L[m][1] = w1 * rs * g; t3L[m][2] = w2v * rs * g;
        const float f = ldf(fc, P0 + m, isf32);
        tbL[m] = g * f * f;
    }
    __syncthreads();
    const int c = lane;
    #pragma unroll 4
    for (int mm = 0; mm < 16; mm++) {
        const int m = w * 16 + mm;
        const float bv = i1bL[m * 64 + c];
        const float coef = bv * tbL[m];
        #pragma unroll
        for (int x = 0; x < 3; x++) {
            const float p3v = ldf(p3, sJL[m] * 192 + x * 64 + c, isf32);
            atomicAdd(&outB[(size_t)sIL[m] * 192 + x * 64 + c],
                      p3v * bv + d3L[m][x] * bv + t3L[m][x] * coef);
        }
    }
}

// ---------------- per-atom epilogue ----------------
__global__ __launch_bounds__(256) void k_final(
    const float* __restrict__ p1scat, const float* __restrict__ p3acc,
    const float* __restrict__ wbuf, const int* __restrict__ flagp,
    void* __restrict__ out)
{
    const float* ppW1 = wbuf + W_PPOSTW1;
    const float* ppW2 = wbuf + W_PPOSTW2;
    const float* eqW  = wbuf + W_EQW;
    const float* q1W  = wbuf + W_Q1W;
    const float* q1b  = wbuf + W_Q1B;
    const float* q2W  = wbuf + W_Q2W;
    const float* q2b  = wbuf + W_Q2B;
    const int isf32 = *flagp;

    __shared__ float s1[4][128];
    __shared__ float hA[4][64];
    __shared__ float cat[4][128];
    __shared__ float p3a[4][192];
    const int t = threadIdx.x;
    const int slot = t >> 6, c = t & 63;
    const int atom = blockIdx.x * 4 + slot;

    s1[slot][c]        = p1scat[atom * 128 + c];
    s1[slot][64 + c]   = p1scat[atom * 128 + 64 + c];
    p3a[slot][c]       = p3acc[atom * 192 + c];
    p3a[slot][64 + c]  = p3acc[atom * 192 + 64 + c];
    p3a[slot][128 + c] = p3acc[atom * 192 + 128 + c];
    __syncthreads();

    float acc = 0.f;
    for (int k = 0; k < 128; k++) acc += s1[slot][k] * ppW1[k * 64 + c];
    hA[slot][c] = tanh_fast(acc);
    __syncthreads();
    acc = 0.f;
    for (int k = 0; k < 64; k++) acc += hA[slot][k] * ppW2[k * 64 + c];
    cat[slot][c] = tanh_fast(acc);

    float pn[3];
    float dot = 0.f;
    #pragma unroll
    for (int x = 0; x < 3; x++) {
        float a = 0.f;
        for (int k = 0; k < 64; k++) a += p3a[slot][x * 64 + k] * eqW[k * 64 + c];
        pn[x] = a;
        dot += a * a;
    }
    cat[slot][64 + c] = dot;
    __syncthreads();

    acc = q1b[c];
    for (int k = 0; k < 128; k++) acc += cat[slot][k] * q1W[k * 64 + c];
    __syncthreads();
    hA[slot][c] = tanh_fast(acc);
    __syncthreads();

    float g1acc = q2b[c], g3acc = q2b[c + 64];
    for (int k = 0; k < 64; k++) {
        const float hv = hA[slot][k];
        g1acc += hv * q2W[k * 128 + c];
        g3acc += hv * q2W[k * 128 + c + 64];
    }
    const float g1 = tanh_fast(g1acc);
    const float g3 = tanh_fast(g3acc);
    if (isf32) {
        float* p1o = (float*)out;
        float* p3o = p1o + 640000;
        p1o[atom * 64 + c] = g1;
        #pragma unroll
        for (int x = 0; x < 3; x++) p3o[atom * 192 + x * 64 + c] = pn[x] * g3;
    } else {
        __hip_bfloat16* p1o = (__hip_bfloat16*)out;
        __hip_bfloat16* p3o = p1o + 640000;
        p1o[atom * 64 + c] = __float2bfloat16(g1);
        #pragma unroll
        for (int x = 0; x < 3; x++) p3o[atom * 192 + x * 64 + c] = __float2bfloat16(pn[x] * g3);
    }
}

// ---------------- v scatter (atomic fallback path only) ----------------
__global__ __launch_bounds__(256) void k_vscat(
    const int* __restrict__ ind2, const void* __restrict__ d3,
    const void* __restrict__ fc, const int* __restrict__ flagp, float* __restrict__ v)
{
    const int p = blockIdx.x * 256 + threadIdx.x;
    if (p >= N_PAIRS) return;
    const int isf32 = *flagp;
    const int ia = ind2[2 * p];
    const float f = ldf(fc, p, isf32);
    atomicAdd(&v[ia * 3 + 0], ldf(d3, p * 3 + 0, isf32) * f);
    atomicAdd(&v[ia * 3 + 1], ldf(d3, p * 3 + 1, isf32) * f);
    atomicAdd(&v[ia * 3 + 2], ldf(d3, p * 3 + 2, isf32) * f);
}

extern "C" void kernel_launch(void* const* d_in, const int* in_sizes, int n_in,
                              void* d_out, int out_size, void* d_ws, size_t ws_size,
                              hipStream_t stream)
{
    const int* ind2 = (const int*)d_in[0];
    const void* p1    = d_in[1];
    const void* p3    = d_in[2];
    const void* basis = d_in[3];
    const void* d3    = d_in[4];
    const void* fc    = d_in[5];

    char* W = (char*)d_ws;
    float* wbuf  = (float*)(W + 0);                       // 528128 B
    short* piWB2 = (short*)(W + 528128);                  // 655360 B -> 1183488
    short* iiWh  = (short*)(W + 1183488);                 // 16384 B -> 1199872
    short* iiWl  = (short*)(W + 1199872);                 // 16384 B -> 1216256
    unsigned short* p1h = (unsigned short*)(W + 1216256); // 1280000 B -> 2496256
    unsigned short* p1l = (unsigned short*)(W + 2496256); // 1280000 B -> 3776256
    int* flag = (int*)(W + 3776256);                      // 64 B -> 3776320

    const int fused = (ws_size >= 18096384ULL) ? 1 : 0;

    if (fused) {
        int* offs     = (int*)(W + 3776320);      // 40016 B -> pad 3816384
        int* cur      = (int*)(W + 3816384);      // 40000 B -> 3856384
        int* perm     = (int*)(W + 3856384);      // 1280000 B -> 5136384
        int* cnt      = (int*)(W + 5136384);      // 40000 B -> 5176384
        float* v      = (float*)(W + 5176384);    // 120000 B -> 5296384
        float* p1scat = (float*)(W + 5296384);    // 5120000 B -> 10416384
        float* p3acc  = (float*)(W + 10416384);   // 7680000 B -> ends 18096384

        // one contiguous zero: cnt + v + p1scat + p3acc
        hipMemsetAsync(cnt, 0, 40000 + 120000 + 5120000 + 7680000, stream);
        k_probe_hist_v<<<1250, 256, 0, stream>>>(d3, fc, flag, ind2, cnt, v);
        k_convert_scan<<<517, 256, 0, stream>>>(
            d_in[6], d_in[7], d_in[8], d_in[9], d_in[10], d_in[11], d_in[12],
            d_in[13], d_in[14], d_in[15], d_in[16], d_in[17], d_in[18], d_in[19],
            wbuf, flag, cnt, offs, cur);
        k_prep_scatter<<<4102, 256, 0, stream>>>(wbuf, piWB2, iiWh, iiWl, p1, flag,
                                                 p1h, p1l, ind2, cur, perm);
        k_pairs_fused<<<5000, 256, 0, stream>>>(ind2, basis, d3, fc, perm, p3,
                                                wbuf, piWB2, iiWh, iiWl,
                                                p1h, p1l, flag, v, p1scat, p3acc);
        k_final<<<2500, 256, 0, stream>>>(p1scat, p3acc, wbuf, flag, d_out);
    } else {
        float* v      = (float*)(W + 3776320); // 120000 B -> 3896320
        float* p1scat = (float*)(W + 3896320); // 5120000 B -> 9016320
        float* p3acc  = (float*)(W + 9016320); // 7680000 B -> ends 16696320

        hipMemsetAsync(v, 0, 120000 + 5120000 + 7680000, stream);
        k_probe<<<1, 64, 0, stream>>>(d3, flag);
        k_convert_scan<<<516, 256, 0, stream>>>(
            d_in[6], d_in[7], d_in[8], d_in[9], d_in[10], d_in[11], d_in[12],
            d_in[13], d_in[14], d_in[15], d_in[16], d_in[17], d_in[18], d_in[19],
            wbuf, flag, nullptr, nullptr, nullptr);
        k_prep_scatter<<<2852, 256, 0, stream>>>(wbuf, piWB2, iiWh, iiWl, p1, flag,
                                                 p1h, p1l, nullptr, nullptr, nullptr);
        k_vscat<<<1250, 256, 0, stream>>>(ind2, d3, fc, flag, v);
        k_pairs_atomic<<<5000, 256, 0, stream>>>(ind2, basis, d3, fc, p3,
                                                 wbuf, piWB2, iiWh, iiWl,
                                                 p1h, p1l, flag, v,
                                                 p1scat, p3acc);
        k_final<<<2500, 256, 0, stream>>>(p1scat, p3acc, wbuf, flag, d_out);
    }
}